// Round 8
// baseline (92.571 us; speedup 1.0000x reference)
//
#include <hip/hip_runtime.h>
#include <cstdint>

typedef unsigned int u32;
typedef unsigned long long u64;

constexpr int B_ = 8;
constexpr int P_ = 16384;
constexpr int K_ = 100;
constexpr int M_ = P_ * 4;            // candidates per image, j = p*4+(cls-1)
constexpr int TSEL = 192;             // selection target
constexpr int CAP = 256;              // selection capacity (= one resolve chunk)
constexpr int NBP = 576;              // hist bins: (bits>>16) - BASE16, 64 lanes x 9
constexpr u32 BASE16 = 0x3D4Cu;       // bits(0.05f) >> 16
constexpr float SCORE_T = 0.05f;
constexpr float CLIPV = 4.135166556742356f;  // log(1000/16)

// swizzled candidate slot: rotate low-6 bits by 4*(group) -> the 4 simultaneous
// row-group reads in the pairwise phase hit 2 banks (2-way == free) not 4-way.
__device__ inline int aphys(int i) {
  return (i < CAP) ? ((((i & 63) + ((i >> 6) << 2)) & 63) | (i & 192)) : i;
}

// ---------------------------------------------------------------------------
// Kernel 0: zero hist + selcnt (4616 words). Replaces the pathological
// runtime fillBuffer (40 us for 144 KB in R7).
// ---------------------------------------------------------------------------
__global__ __launch_bounds__(256) void zero_kernel(u32* __restrict__ p, int nword) {
  const int i = blockIdx.x * 256 + threadIdx.x;
  if (i < nword) p[i] = 0u;
}

// ---------------------------------------------------------------------------
// Kernel 1 (wide, 512 blocks): softmax + decode + clip; store scores, boxes,
// per-block max coord; global-atomic per-image histogram of score bits (>>16).
// ---------------------------------------------------------------------------
__global__ __launch_bounds__(256) void prep_kernel(
    const float* __restrict__ logits,     // [N,5]
    const float* __restrict__ boxreg,     // [N,20]
    const float* __restrict__ props,      // [N,4]
    const int*  __restrict__ image_hw,    // {H,W}
    float* __restrict__ wboxes,           // [B*M,4]
    float* __restrict__ wscores,          // [B*M]
    float* __restrict__ wblockmax,        // [512]
    u32*   __restrict__ hist)             // [B*NBP], pre-zeroed
{
  const int n = blockIdx.x * 256 + threadIdx.x;   // 512*256 == B*P
  const int b = n >> 14;

  float l[5];
#pragma unroll
  for (int i = 0; i < 5; ++i) l[i] = logits[n * 5 + i];
  float mx = l[0];
#pragma unroll
  for (int i = 1; i < 5; ++i) mx = fmaxf(mx, l[i]);
  float e[5]; float ssum = 0.f;
#pragma unroll
  for (int i = 0; i < 5; ++i) { e[i] = expf(l[i] - mx); ssum += e[i]; }

  const float4 pr = reinterpret_cast<const float4*>(props)[n];
  const float w  = pr.z - pr.x;
  const float h  = pr.w - pr.y;
  const float cx = pr.x + 0.5f * w;
  const float cy = pr.y + 0.5f * h;
  const float Hf = (float)image_hw[0];
  const float Wf = (float)image_hw[1];

  float bmax = 0.f;
  float sc[4];
#pragma unroll
  for (int c = 1; c < 5; ++c) {
    const float4 rel = reinterpret_cast<const float4*>(boxreg)[n * 5 + c];
    const float dx = rel.x / 10.0f;
    const float dy = rel.y / 10.0f;
    const float dw = fminf(rel.z / 5.0f, CLIPV);
    const float dh = fminf(rel.w / 5.0f, CLIPV);
    const float pcx = dx * w + cx;
    const float pcy = dy * h + cy;
    const float pw = expf(dw) * w;
    const float ph = expf(dh) * h;
    float x1 = pcx - 0.5f * pw, y1 = pcy - 0.5f * ph;
    float x2 = pcx + 0.5f * pw, y2 = pcy + 0.5f * ph;
    x1 = fminf(fmaxf(x1, 0.f), Wf);
    x2 = fminf(fmaxf(x2, 0.f), Wf);
    y1 = fminf(fmaxf(y1, 0.f), Hf);
    y2 = fminf(fmaxf(y2, 0.f), Hf);
    reinterpret_cast<float4*>(wboxes)[n * 4 + (c - 1)] = make_float4(x1, y1, x2, y2);
    bmax = fmaxf(bmax, fmaxf(fmaxf(x1, x2), fmaxf(y1, y2)));
    const float sv = e[c] / ssum;
    sc[c - 1] = sv;
    if (sv > SCORE_T) {
      u32 bin = (__float_as_uint(sv) >> 16) - BASE16;
      if (bin >= (u32)NBP) bin = NBP - 1;
      atomicAdd(&hist[b * NBP + bin], 1u);
    }
  }
  reinterpret_cast<float4*>(wscores)[n] = make_float4(sc[0], sc[1], sc[2], sc[3]);

  __shared__ float red[256];
  red[threadIdx.x] = bmax;
  __syncthreads();
#pragma unroll
  for (int off = 128; off > 0; off >>= 1) {
    if (threadIdx.x < off) red[threadIdx.x] = fmaxf(red[threadIdx.x], red[threadIdx.x + off]);
    __syncthreads();
  }
  if (threadIdx.x == 0) wblockmax[blockIdx.x] = red[0];
}

// ---------------------------------------------------------------------------
// Kernel 2 (wide, 512 blocks): wave 0 computes this image's exact threshold X
// from the 576-bin histogram (9 bins/lane, one-wave suffix scan), then all
// threads append keys with bits >= X to the per-image list (count <= CAP).
// ---------------------------------------------------------------------------
__global__ __launch_bounds__(256) void compact_kernel(
    const float* __restrict__ wscores, const u32* __restrict__ hist,
    u32* __restrict__ Xthr, int* __restrict__ remv,
    int* __restrict__ selcnt, u64* __restrict__ keybuf)
{
  const int n = blockIdx.x * 256 + threadIdx.x;
  const int b = n >> 14;
  const int t = threadIdx.x;
  __shared__ u32 Xs;

  if (t < 64) {
    const u32* h = hist + b * NBP;
    const int lo = NBP - t * 9 - 9;        // lane 0 owns the TOP 9 bins
    u32 hb[9]; int mysum = 0;
#pragma unroll
    for (int q = 0; q < 9; ++q) { hb[q] = h[lo + q]; mysum += (int)hb[q]; }
    int inc = mysum;                        // suffix-from-top inclusive scan
#pragma unroll
    for (int off = 1; off < 64; off <<= 1) {
      const int v = __shfl_up(inc, off);
      if (t >= off) inc += v;
    }
    const int tot = __shfl(inc, 63);
    const int pre = inc - mysum;
    if (tot < TSEL) {
      if (t == 63) { Xs = BASE16 << 16; Xthr[b] = BASE16 << 16; remv[b] = 0; }
    } else if (pre < TSEL && inc >= TSEL) { // unique boundary lane
      int cum = pre, kb = lo, qsel = 8;
      for (int q = 8; q >= 0; --q) {        // top bin of lane-chunk first
        cum += (int)hb[q];
        if (cum >= TSEL) { kb = lo + q; qsel = q; break; }
      }
      int C = cum;
      u32 Xbin;
      if (C > CAP) { C -= (int)hb[qsel]; Xbin = (u32)(kb + 1); }  // exclude tie-bin
      else Xbin = (u32)kb;
      const u32 Xv = (BASE16 + Xbin) << 16;
      Xs = Xv; Xthr[b] = Xv; remv[b] = tot - C;
    }
  }
  __syncthreads();
  const u32 X = Xs;

  const float4 v = reinterpret_cast<const float4*>(wscores)[n];
  const float ss[4] = {v.x, v.y, v.z, v.w};
  const int j0 = (n & (P_ - 1)) * 4;
#pragma unroll
  for (int c = 0; c < 4; ++c) {
    if (ss[c] > SCORE_T) {
      const u32 bb = __float_as_uint(ss[c]);
      if (bb >= X) {
        const int pos = atomicAdd(&selcnt[b], 1);
        if (pos < CAP) keybuf[b * CAP + pos] = ((u64)bb << 16) | (u64)(65535 - (j0 + c));
      }
    }
  }
}

// ---------------------------------------------------------------------------
// Kernel 3 (8 blocks x 512): O(CAP) only — rank sort, box gather, pairwise
// masks, parallel greedy fixpoint, output gather (+ exactness slow path).
// ---------------------------------------------------------------------------
__global__ __launch_bounds__(512) void nms_kernel(
    const float* __restrict__ wboxes, const float* __restrict__ wscores,
    const float* __restrict__ wblockmax, const u32* __restrict__ Xthr,
    const int* __restrict__ remv, const int* __restrict__ selcnt,
    const u64* __restrict__ keybuf,
    const float* __restrict__ handside, const float* __restrict__ dxdymag,
    const float* __restrict__ contact, float* __restrict__ out)
{
  const int b = blockIdx.x, t = threadIdx.x;
  const float4* boxes4 = reinterpret_cast<const float4*>(wboxes);
  const float4* sc4 = reinterpret_cast<const float4*>(wscores) + (size_t)b * (M_ / 4);
  const u32 X = Xthr[b];

  __shared__ float maxv_s;
  __shared__ u64   kall[CAP];
  __shared__ u64   skey[CAP];
  __shared__ float4 cb4[CAP + K_];     // offset coords, swizzled slots
  __shared__ float carea[CAP + K_];
  __shared__ float cscf[CAP + K_];
  __shared__ int   cj[CAP + K_];
  __shared__ u64   supmask[CAP * 4];
  __shared__ u64   km[4];
  __shared__ int   chg;
  __shared__ int   kidx[K_];
  __shared__ int   kcount_s, nslow_s;
  __shared__ u64   red2[512];
  __shared__ u64   bitmap[1024];

  if (t < 64) {                        // per-image max coord from block maxima
    float v = wblockmax[b * 64 + t];
#pragma unroll
    for (int off = 32; off > 0; off >>= 1) v = fmaxf(v, __shfl_xor(v, off));
    if (t == 0) maxv_s = v;
  }
  if (t == 0) { kcount_s = 0; nslow_s = 0; }
  const int C = min(selcnt[b], CAP);
  if (t < CAP) kall[t] = (t < C) ? keybuf[b * CAP + t] : 0ull;
  __syncthreads();
  const float maxv1 = maxv_s + 1.0f;   // (boxes.max() + 1.0)

  // ---- rank-by-counting sort (unique keys, descending) ----
  if (t < CAP) {
    const u64 my = kall[t];
    u32 r = 0;
    for (int u = 0; u < CAP; ++u) r += (kall[u] > my) ? 1u : 0u;
    if (t < C) skey[r] = my;
  }
  __syncthreads();

  // ---- candidate setup from stored boxes ----
  if (t < C) {
    const u64 key = skey[t];
    const int j = 65535 - (int)(key & 0xFFFFull);
    const int cls = (j & 3) + 1;
    const float4 bx = boxes4[(size_t)b * M_ + j];
    const float offv = (float)cls * maxv1;
    const float ox1 = bx.x + offv, oy1 = bx.y + offv;
    const float ox2 = bx.z + offv, oy2 = bx.w + offv;
    const int ph = aphys(t);
    cb4[ph] = make_float4(ox1, oy1, ox2, oy2);
    carea[ph] = (ox2 - ox1) * (oy2 - oy1);
    cscf[ph] = __uint_as_float((u32)(key >> 16));
    cj[ph] = j;
  }
  __syncthreads();

  // ---- pairwise suppression rows (self excluded) ----
  for (int task = t; task < C * 4; task += 512) {
    const int i = task >> 2, wq = task & 3;
    const float4 ib = cb4[aphys(i)];
    const float ia = carea[aphys(i)];
    u64 m = 0;
    const int qb = wq * 64, qe = min(qb + 64, C);
    for (int q = qb; q < qe; ++q) {
      if (q == i) continue;
      const int qp = aphys(q);
      const float4 qbx = cb4[qp];
      const float ltx = fmaxf(ib.x, qbx.x);
      const float lty = fmaxf(ib.y, qbx.y);
      const float rbx = fminf(ib.z, qbx.z);
      const float rby = fminf(ib.w, qbx.w);
      const float iw = fmaxf(rbx - ltx, 0.f);
      const float ih = fmaxf(rby - lty, 0.f);
      const float inter = iw * ih;
      const float iou = inter / (ia + carea[qp] - inter);  // a1+a2-inter
      if (iou > 0.5f) m |= 1ull << (q - qb);               // NaN -> false (ref)
    }
    supmask[i * 4 + wq] = m;
  }
  __syncthreads();

  // ---- parallel greedy fixpoint (unique fixpoint == greedy) ----
  const int wi = t >> 6, bi = t & 63;
  const u64 lowmask = bi ? (~0ull >> (64 - bi)) : 0ull;
  u64 rb0 = 0, rb1 = 0, rb2 = 0, rb3 = 0;
  const bool alive = (t < C);
  if (t < CAP) {
    rb0 = supmask[t * 4 + 0];
    rb1 = supmask[t * 4 + 1];
    rb2 = supmask[t * 4 + 2];
    rb3 = supmask[t * 4 + 3];
    const u64 m0 = (wi > 0) ? ~0ull : lowmask;
    const u64 m1 = (wi > 1) ? ~0ull : ((wi == 1) ? lowmask : 0ull);
    const u64 m2 = (wi > 2) ? ~0ull : ((wi == 2) ? lowmask : 0ull);
    const u64 m3 = (wi == 3) ? lowmask : 0ull;
    rb0 &= m0; rb1 &= m1; rb2 &= m2; rb3 &= m3;   // suppressors j < i only
    const u64 bal = __ballot(alive ? 1 : 0);
    if (bi == 0) km[wi] = bal;
  }
  __syncthreads();
  while (true) {
    if (t == 0) chg = 0;
    __syncthreads();
    u64 nb = 0;
    if (t < CAP) {
      const u64 k0 = km[0], k1 = km[1], k2 = km[2], k3 = km[3];
      const bool sup = ((rb0 & k0) | (rb1 & k1) | (rb2 & k2) | (rb3 & k3)) != 0ull;
      const bool kn = alive && !sup;
      nb = __ballot(kn ? 1 : 0);
      if (bi == 0 && nb != km[wi]) chg = 1;
    }
    __syncthreads();
    if (t < CAP && bi == 0) km[wi] = nb;
    __syncthreads();
    if (!chg) break;
  }

  // ---- extract keeps in index order (== greedy pop order) ----
  if (t < CAP) {
    const u64 kw = km[wi];
    if ((kw >> bi) & 1ull) {
      int pb = 0;
      if (wi > 0) pb += __popcll(km[0]);
      if (wi > 1) pb += __popcll(km[1]);
      if (wi > 2) pb += __popcll(km[2]);
      pb += __popcll(kw & lowmask);
      if (pb < K_) kidx[pb] = t;
    }
    if (t == 0) {
      kcount_s = min(__popcll(km[0]) + __popcll(km[1]) +
                     __popcll(km[2]) + __popcll(km[3]), K_);
    }
  }
  __syncthreads();

  // ---- slow-path continuation (exactness; skipped on benign data) ----
  if (kcount_s < K_ && remv[b] > 0) {
    for (int i = t; i < 1024; i += 512) bitmap[i] = 0ull;
    __syncthreads();
    while (true) {
      u64 best = 0ull;
      for (int i = t; i < M_ / 4; i += 512) {
        const float4 v = sc4[i];
        const float ss[4] = {v.x, v.y, v.z, v.w};
#pragma unroll
        for (int c = 0; c < 4; ++c) {
          if (ss[c] > SCORE_T) {
            const u32 bb = __float_as_uint(ss[c]);
            if (bb < X) {
              const int j = i * 4 + c;
              if (!((bitmap[j >> 6] >> (j & 63)) & 1ull)) {
                const u64 key = ((u64)bb << 16) | (u64)(65535 - j);
                if (key > best) best = key;
              }
            }
          }
        }
      }
      red2[t] = best;
      __syncthreads();
      for (int off = 256; off > 0; off >>= 1) {
        if (t < off && red2[t + off] > red2[t]) red2[t] = red2[t + off];
        __syncthreads();
      }
      const u64 wkey = red2[0];
      if (wkey == 0ull) break;
      if (t == 0) {
        const int j = 65535 - (int)(wkey & 0xFFFFull);
        bitmap[j >> 6] |= 1ull << (j & 63);
        const int cls = (j & 3) + 1;
        const float4 bx = boxes4[(size_t)b * M_ + j];
        const float offv = (float)cls * maxv1;
        const float ox1 = bx.x + offv, oy1 = bx.y + offv;
        const float ox2 = bx.z + offv, oy2 = bx.w + offv;
        const float ar = (ox2 - ox1) * (oy2 - oy1);
        bool sup = false;
        for (int k2 = 0; k2 < kcount_s; ++k2) {
          const int ki = aphys(kidx[k2]);
          const float4 kb = cb4[ki];
          const float ltx = fmaxf(kb.x, ox1);
          const float lty = fmaxf(kb.y, oy1);
          const float rbx = fminf(kb.z, ox2);
          const float rby = fminf(kb.w, oy2);
          const float iw = fmaxf(rbx - ltx, 0.f);
          const float ih = fmaxf(rby - lty, 0.f);
          const float inter = iw * ih;
          const float iou = inter / (carea[ki] + ar - inter);
          if (iou > 0.5f) { sup = true; break; }
        }
        if (!sup) {
          const int slot = CAP + nslow_s;        // aphys(slot) == slot
          cb4[slot] = make_float4(ox1, oy1, ox2, oy2);
          carea[slot] = ar;
          cscf[slot] = __uint_as_float((u32)(wkey >> 16));
          cj[slot] = j;
          kidx[kcount_s] = slot;
          ++nslow_s;
          ++kcount_s;
        }
      }
      __syncthreads();
      if (kcount_s >= K_) break;
    }
    __syncthreads();
  }
  __syncthreads();

  // ---- gather outputs ----
  const int kc = kcount_s;
  if (t < K_) {
    const int r = t;
    float ob0 = 0.f, ob1 = 0.f, ob2 = 0.f, ob3 = 0.f;
    float osc = 0.f, olab = 0.f, oside = 0.f;
    float od0 = 0.f, od1 = 0.f, od2 = 0.f;
    float ocon = 0.f, okeep = 0.f;
    if (r < kc) {
      const int idx = kidx[r];
      const int ph = aphys(idx);
      const int j = cj[ph];
      const int cls = (j & 3) + 1;
      const int n = b * P_ + (j >> 2);
      const float4 bx = boxes4[(size_t)b * M_ + j];   // unshifted output box
      ob0 = bx.x; ob1 = bx.y; ob2 = bx.z; ob3 = bx.w;
      osc = cscf[ph];
      olab = (float)cls;
      oside = (handside[n * 5 + cls] > 0.f) ? 1.f : 0.f;  // sigmoid>0.5 <=> x>0
      od0 = dxdymag[n * 15 + cls * 3 + 0];
      od1 = dxdymag[n * 15 + cls * 3 + 1];
      od2 = dxdymag[n * 15 + cls * 3 + 2];
      float bvv = contact[n * 25 + cls * 5 + 0];
      int best = 0;
#pragma unroll
      for (int i = 1; i < 5; ++i) {
        const float ci = contact[n * 25 + cls * 5 + i];
        if (ci > bvv) { bvv = ci; best = i; }
      }
      ocon = (float)best;
      okeep = 1.f;
    }
    const int gb = b * K_ + r;
    out[gb * 4 + 0] = ob0;
    out[gb * 4 + 1] = ob1;
    out[gb * 4 + 2] = ob2;
    out[gb * 4 + 3] = ob3;
    out[3200 + gb] = osc;
    out[4000 + gb] = olab;
    out[4800 + gb] = oside;
    out[5600 + gb * 3 + 0] = od0;
    out[5600 + gb * 3 + 1] = od1;
    out[5600 + gb * 3 + 2] = od2;
    out[8000 + gb] = ocon;
    out[8800 + gb] = okeep;
  }
}

// ---------------------------------------------------------------------------
extern "C" void kernel_launch(void* const* d_in, const int* in_sizes, int n_in,
                              void* d_out, int out_size, void* d_ws, size_t ws_size,
                              hipStream_t stream) {
  const float* class_logits = (const float*)d_in[0];
  const float* box_reg      = (const float*)d_in[1];
  const float* handside     = (const float*)d_in[2];
  const float* dxdymag      = (const float*)d_in[3];
  const float* contact      = (const float*)d_in[4];
  const float* proposals    = (const float*)d_in[5];
  const int*   image_hw     = (const int*)d_in[6];
  float* out = (float*)d_out;

  char* ws = (char*)d_ws;
  u32*   hist      = (u32*)  ws;                       // 8*576*4 = 18432 B [zeroed]
  int*   selcnt    = (int*)  (ws + 18432);             // 32 B              [zeroed]
  u32*   Xthr      = (u32*)  (ws + 18464);             // 32 B
  int*   remv      = (int*)  (ws + 18496);             // 32 B
  float* wblockmax = (float*)(ws + 18560);             // 2 KiB
  u64*   keybuf    = (u64*)  (ws + 20608);             // 16 KiB
  float* wscores   = (float*)(ws + 65536);             // 2 MiB
  float* wboxes    = (float*)(ws + 65536 + 2097152);   // 8 MiB (ends ~10.1 MiB)

  constexpr int ZW = (8 * NBP + 8);                    // hist + selcnt words
  zero_kernel<<<dim3((ZW + 255) / 256), dim3(256), 0, stream>>>(hist, ZW);
  prep_kernel<<<dim3(512), dim3(256), 0, stream>>>(
      class_logits, box_reg, proposals, image_hw, wboxes, wscores, wblockmax, hist);
  compact_kernel<<<dim3(512), dim3(256), 0, stream>>>(
      wscores, hist, Xthr, remv, selcnt, keybuf);
  nms_kernel<<<dim3(B_), dim3(512), 0, stream>>>(
      wboxes, wscores, wblockmax, Xthr, remv, selcnt, keybuf,
      handside, dxdymag, contact, out);
}

// Round 9
// 53.189 us; speedup vs baseline: 1.7404x; 1.7404x over previous
//
#include <hip/hip_runtime.h>
#include <cstdint>

typedef unsigned int u32;
typedef unsigned long long u64;

constexpr int B_ = 8;
constexpr int P_ = 16384;
constexpr int K_ = 100;
constexpr int M_ = P_ * 4;            // candidates per image, j = p*4+(cls-1)
constexpr int TSEL = 192;             // selection target
constexpr int CAP = 256;              // selection capacity (= one resolve chunk)
constexpr int NBP = 576;              // hist bins: (bits>>16) - BASE16
constexpr u32 BASE16 = 0x3D4Cu;       // bits(0.05f) >> 16
constexpr float SCORE_T = 0.05f;
constexpr float CLIPV = 4.135166556742356f;  // log(1000/16)

// swizzled candidate slot: rotate low-6 bits by 4*(group) -> the 4 simultaneous
// row-group reads in the pairwise phase hit 2 banks (2-way == free) not 4-way.
__device__ inline int aphys(int i) {
  return (i < CAP) ? ((((i & 63) + ((i >> 6) << 2)) & 63) | (i & 192)) : i;
}

// ---------------------------------------------------------------------------
// Kernel 1 (wide, 512 blocks, image-pure blocks): softmax + decode + clip;
// store scores, boxes, per-block max; per-block LDS histogram flushed as plain
// stores (NO global atomics — R8's global-atomic hist cost ~50+ us).
// ---------------------------------------------------------------------------
__global__ __launch_bounds__(256) void prep_kernel(
    const float* __restrict__ logits,     // [N,5]
    const float* __restrict__ boxreg,     // [N,20]
    const float* __restrict__ props,      // [N,4]
    const int*  __restrict__ image_hw,    // {H,W}
    float* __restrict__ wboxes,           // [B*M,4]
    float* __restrict__ wscores,          // [B*M]
    float* __restrict__ wblockmax,        // [512]
    u32*   __restrict__ bhist)            // [512][NBP] per-block hists
{
  __shared__ u32 lh[NBP];
  __shared__ float red[256];
  for (int i = threadIdx.x; i < NBP; i += 256) lh[i] = 0u;
  __syncthreads();

  const int n = blockIdx.x * 256 + threadIdx.x;   // 512*256 == B*P

  float l[5];
#pragma unroll
  for (int i = 0; i < 5; ++i) l[i] = logits[n * 5 + i];
  float mx = l[0];
#pragma unroll
  for (int i = 1; i < 5; ++i) mx = fmaxf(mx, l[i]);
  float e[5]; float ssum = 0.f;
#pragma unroll
  for (int i = 0; i < 5; ++i) { e[i] = expf(l[i] - mx); ssum += e[i]; }

  const float4 pr = reinterpret_cast<const float4*>(props)[n];
  const float w  = pr.z - pr.x;
  const float h  = pr.w - pr.y;
  const float cx = pr.x + 0.5f * w;
  const float cy = pr.y + 0.5f * h;
  const float Hf = (float)image_hw[0];
  const float Wf = (float)image_hw[1];

  float bmax = 0.f;
  float sc[4];
#pragma unroll
  for (int c = 1; c < 5; ++c) {
    const float4 rel = reinterpret_cast<const float4*>(boxreg)[n * 5 + c];
    const float dx = rel.x / 10.0f;
    const float dy = rel.y / 10.0f;
    const float dw = fminf(rel.z / 5.0f, CLIPV);
    const float dh = fminf(rel.w / 5.0f, CLIPV);
    const float pcx = dx * w + cx;
    const float pcy = dy * h + cy;
    const float pw = expf(dw) * w;
    const float ph = expf(dh) * h;
    float x1 = pcx - 0.5f * pw, y1 = pcy - 0.5f * ph;
    float x2 = pcx + 0.5f * pw, y2 = pcy + 0.5f * ph;
    x1 = fminf(fmaxf(x1, 0.f), Wf);
    x2 = fminf(fmaxf(x2, 0.f), Wf);
    y1 = fminf(fmaxf(y1, 0.f), Hf);
    y2 = fminf(fmaxf(y2, 0.f), Hf);
    reinterpret_cast<float4*>(wboxes)[n * 4 + (c - 1)] = make_float4(x1, y1, x2, y2);
    bmax = fmaxf(bmax, fmaxf(fmaxf(x1, x2), fmaxf(y1, y2)));
    const float sv = e[c] / ssum;
    sc[c - 1] = sv;
    if (sv > SCORE_T) {
      u32 bin = (__float_as_uint(sv) >> 16) - BASE16;
      if (bin >= (u32)NBP) bin = NBP - 1;
      atomicAdd(&lh[bin], 1u);              // LDS atomic: cheap
    }
  }
  reinterpret_cast<float4*>(wscores)[n] = make_float4(sc[0], sc[1], sc[2], sc[3]);

  __syncthreads();
  for (int i = threadIdx.x; i < NBP; i += 256)    // plain coalesced flush
    bhist[(size_t)blockIdx.x * NBP + i] = lh[i];

  red[threadIdx.x] = bmax;
  __syncthreads();
#pragma unroll
  for (int off = 128; off > 0; off >>= 1) {
    if (threadIdx.x < off) red[threadIdx.x] = fmaxf(red[threadIdx.x], red[threadIdx.x + off]);
    __syncthreads();
  }
  if (threadIdx.x == 0) wblockmax[blockIdx.x] = red[0];
}

// ---------------------------------------------------------------------------
// Kernel 2 (8 blocks x 512): aggregate per-block hists -> exact threshold X,
// C, rem; per-prep-block exclusive offsets so compact needs no atomics.
// ---------------------------------------------------------------------------
__global__ __launch_bounds__(512) void thresh_kernel(
    const u32* __restrict__ bhist, u32* __restrict__ Xthr, int* __restrict__ Carr,
    int* __restrict__ remv, int* __restrict__ offs)
{
  const int b = blockIdx.x, t = threadIdx.x;
  __shared__ u32 agg[NBP];
  __shared__ u32 X_s;
  __shared__ int binX_s, C_sh, rem_sh;
  __shared__ int sg[64];

  // aggregate over the image's 64 prep blocks
  for (int bin = t; bin < NBP; bin += 512) {
    u32 s = 0;
    const u32* h = bhist + (size_t)(b * 64) * NBP + bin;
    for (int g = 0; g < 64; ++g) s += h[(size_t)g * NBP];
    agg[bin] = s;
  }
  __syncthreads();

  // one-wave suffix scan (lane 0 owns the TOP 9 bins)
  if (t < 64) {
    const int lo = NBP - t * 9 - 9;
    u32 hb[9]; int mysum = 0;
#pragma unroll
    for (int q = 0; q < 9; ++q) { hb[q] = agg[lo + q]; mysum += (int)hb[q]; }
    int inc = mysum;
#pragma unroll
    for (int off = 1; off < 64; off <<= 1) {
      const int v = __shfl_up(inc, off);
      if (t >= off) inc += v;
    }
    const int tot = __shfl(inc, 63);
    const int pre = inc - mysum;
    if (tot < TSEL) {
      if (t == 63) { X_s = BASE16 << 16; binX_s = 0; C_sh = tot; rem_sh = 0; }
    } else if (pre < TSEL && inc >= TSEL) {   // unique boundary lane
      int cum = pre, kb = lo, qsel = 8;
      for (int q = 8; q >= 0; --q) {
        cum += (int)hb[q];
        if (cum >= TSEL) { kb = lo + q; qsel = q; break; }
      }
      int C = cum;
      u32 Xbin;
      if (C > CAP) { C -= (int)hb[qsel]; Xbin = (u32)(kb + 1); }  // exclude tie-bin
      else Xbin = (u32)kb;
      X_s = (BASE16 + Xbin) << 16;
      binX_s = (int)Xbin; C_sh = C; rem_sh = tot - C;
    }
  }
  __syncthreads();
  const int binX = binX_s;

  // per-prep-block counts above binX (8 lanes per block g), then offsets
  {
    const int g = t >> 3, lsub = t & 7;
    const u32* h = bhist + (size_t)(b * 64 + g) * NBP;
    int cg = 0;
    for (int bin = binX + lsub; bin < NBP; bin += 8) cg += (int)h[bin];
#pragma unroll
    for (int off = 1; off < 8; off <<= 1) cg += __shfl_xor(cg, off);
    if (lsub == 0) sg[g] = cg;
  }
  __syncthreads();
  if (t < 64) {
    const int v = sg[t];
    int inc = v;
#pragma unroll
    for (int off = 1; off < 64; off <<= 1) {
      const int u = __shfl_up(inc, off);
      if (t >= off) inc += u;
    }
    offs[b * 64 + t] = inc - v;               // exclusive prefix
  }
  if (t == 0) { Xthr[b] = X_s; Carr[b] = C_sh; remv[b] = rem_sh; }
}

// ---------------------------------------------------------------------------
// Kernel 3 (wide, 512 blocks): append keys >= X at precomputed offsets.
// LDS counter only — no global atomics, overflow impossible (sum == C <= CAP).
// ---------------------------------------------------------------------------
__global__ __launch_bounds__(256) void compact_kernel(
    const float* __restrict__ wscores, const u32* __restrict__ Xthr,
    const int* __restrict__ offs, u64* __restrict__ keybuf)
{
  const int blk = blockIdx.x;
  const int b = blk >> 6;
  const int n = blk * 256 + threadIdx.x;
  const u32 X = Xthr[b];
  __shared__ int cnt;
  if (threadIdx.x == 0) cnt = 0;
  __syncthreads();
  const int base = b * CAP + offs[blk];

  const float4 v = reinterpret_cast<const float4*>(wscores)[n];
  const float ss[4] = {v.x, v.y, v.z, v.w};
  const int j0 = (n & (P_ - 1)) * 4;
#pragma unroll
  for (int c = 0; c < 4; ++c) {
    if (ss[c] > SCORE_T) {
      const u32 bb = __float_as_uint(ss[c]);
      if (bb >= X) {
        const int pos = atomicAdd(&cnt, 1);   // LDS atomic
        keybuf[base + pos] = ((u64)bb << 16) | (u64)(65535 - (j0 + c));
      }
    }
  }
}

// ---------------------------------------------------------------------------
// Kernel 4 (8 blocks x 512): O(CAP) only — rank sort, box gather, pairwise
// masks, parallel greedy fixpoint, output gather (+ exactness slow path).
// ---------------------------------------------------------------------------
__global__ __launch_bounds__(512) void nms_kernel(
    const float* __restrict__ wboxes, const float* __restrict__ wscores,
    const float* __restrict__ wblockmax, const u32* __restrict__ Xthr,
    const int* __restrict__ remv, const int* __restrict__ Carr,
    const u64* __restrict__ keybuf,
    const float* __restrict__ handside, const float* __restrict__ dxdymag,
    const float* __restrict__ contact, float* __restrict__ out)
{
  const int b = blockIdx.x, t = threadIdx.x;
  const float4* boxes4 = reinterpret_cast<const float4*>(wboxes);
  const float4* sc4 = reinterpret_cast<const float4*>(wscores) + (size_t)b * (M_ / 4);
  const u32 X = Xthr[b];

  __shared__ float maxv_s;
  __shared__ u64   kall[CAP];
  __shared__ u64   skey[CAP];
  __shared__ float4 cb4[CAP + K_];     // offset coords, swizzled slots
  __shared__ float carea[CAP + K_];
  __shared__ float cscf[CAP + K_];
  __shared__ int   cj[CAP + K_];
  __shared__ u64   supmask[CAP * 4];
  __shared__ u64   km[4];
  __shared__ int   chg;
  __shared__ int   kidx[K_];
  __shared__ int   kcount_s, nslow_s;
  __shared__ u64   red2[512];
  __shared__ u64   bitmap[1024];

  if (t < 64) {                        // per-image max coord from block maxima
    float v = wblockmax[b * 64 + t];
#pragma unroll
    for (int off = 32; off > 0; off >>= 1) v = fmaxf(v, __shfl_xor(v, off));
    if (t == 0) maxv_s = v;
  }
  if (t == 0) { kcount_s = 0; nslow_s = 0; }
  const int C = min(Carr[b], CAP);
  if (t < CAP) kall[t] = (t < C) ? keybuf[b * CAP + t] : 0ull;
  __syncthreads();
  const float maxv1 = maxv_s + 1.0f;   // (boxes.max() + 1.0)

  // ---- rank-by-counting sort (unique keys, descending) ----
  if (t < CAP) {
    const u64 my = kall[t];
    u32 r = 0;
    for (int u = 0; u < CAP; ++u) r += (kall[u] > my) ? 1u : 0u;
    if (t < C) skey[r] = my;
  }
  __syncthreads();

  // ---- candidate setup from stored boxes ----
  if (t < C) {
    const u64 key = skey[t];
    const int j = 65535 - (int)(key & 0xFFFFull);
    const int cls = (j & 3) + 1;
    const float4 bx = boxes4[(size_t)b * M_ + j];
    const float offv = (float)cls * maxv1;
    const float ox1 = bx.x + offv, oy1 = bx.y + offv;
    const float ox2 = bx.z + offv, oy2 = bx.w + offv;
    const int ph = aphys(t);
    cb4[ph] = make_float4(ox1, oy1, ox2, oy2);
    carea[ph] = (ox2 - ox1) * (oy2 - oy1);
    cscf[ph] = __uint_as_float((u32)(key >> 16));
    cj[ph] = j;
  }
  __syncthreads();

  // ---- pairwise suppression rows (self excluded) ----
  for (int task = t; task < C * 4; task += 512) {
    const int i = task >> 2, wq = task & 3;
    const float4 ib = cb4[aphys(i)];
    const float ia = carea[aphys(i)];
    u64 m = 0;
    const int qb = wq * 64, qe = min(qb + 64, C);
    for (int q = qb; q < qe; ++q) {
      if (q == i) continue;
      const int qp = aphys(q);
      const float4 qbx = cb4[qp];
      const float ltx = fmaxf(ib.x, qbx.x);
      const float lty = fmaxf(ib.y, qbx.y);
      const float rbx = fminf(ib.z, qbx.z);
      const float rby = fminf(ib.w, qbx.w);
      const float iw = fmaxf(rbx - ltx, 0.f);
      const float ih = fmaxf(rby - lty, 0.f);
      const float inter = iw * ih;
      const float iou = inter / (ia + carea[qp] - inter);  // a1+a2-inter
      if (iou > 0.5f) m |= 1ull << (q - qb);               // NaN -> false (ref)
    }
    supmask[i * 4 + wq] = m;
  }
  __syncthreads();

  // ---- parallel greedy fixpoint (unique fixpoint == greedy) ----
  const int wi = t >> 6, bi = t & 63;
  const u64 lowmask = bi ? (~0ull >> (64 - bi)) : 0ull;
  u64 rb0 = 0, rb1 = 0, rb2 = 0, rb3 = 0;
  const bool alive = (t < C);
  if (t < CAP) {
    rb0 = supmask[t * 4 + 0];
    rb1 = supmask[t * 4 + 1];
    rb2 = supmask[t * 4 + 2];
    rb3 = supmask[t * 4 + 3];
    const u64 m0 = (wi > 0) ? ~0ull : lowmask;
    const u64 m1 = (wi > 1) ? ~0ull : ((wi == 1) ? lowmask : 0ull);
    const u64 m2 = (wi > 2) ? ~0ull : ((wi == 2) ? lowmask : 0ull);
    const u64 m3 = (wi == 3) ? lowmask : 0ull;
    rb0 &= m0; rb1 &= m1; rb2 &= m2; rb3 &= m3;   // suppressors j < i only
    const u64 bal = __ballot(alive ? 1 : 0);
    if (bi == 0) km[wi] = bal;
  }
  __syncthreads();
  while (true) {
    if (t == 0) chg = 0;
    __syncthreads();
    u64 nb = 0;
    if (t < CAP) {
      const u64 k0 = km[0], k1 = km[1], k2 = km[2], k3 = km[3];
      const bool sup = ((rb0 & k0) | (rb1 & k1) | (rb2 & k2) | (rb3 & k3)) != 0ull;
      const bool kn = alive && !sup;
      nb = __ballot(kn ? 1 : 0);
      if (bi == 0 && nb != km[wi]) chg = 1;
    }
    __syncthreads();
    if (t < CAP && bi == 0) km[wi] = nb;
    __syncthreads();
    if (!chg) break;
  }

  // ---- extract keeps in index order (== greedy pop order) ----
  if (t < CAP) {
    const u64 kw = km[wi];
    if ((kw >> bi) & 1ull) {
      int pb = 0;
      if (wi > 0) pb += __popcll(km[0]);
      if (wi > 1) pb += __popcll(km[1]);
      if (wi > 2) pb += __popcll(km[2]);
      pb += __popcll(kw & lowmask);
      if (pb < K_) kidx[pb] = t;
    }
    if (t == 0) {
      kcount_s = min(__popcll(km[0]) + __popcll(km[1]) +
                     __popcll(km[2]) + __popcll(km[3]), K_);
    }
  }
  __syncthreads();

  // ---- slow-path continuation (exactness; skipped on benign data) ----
  if (kcount_s < K_ && remv[b] > 0) {
    for (int i = t; i < 1024; i += 512) bitmap[i] = 0ull;
    __syncthreads();
    while (true) {
      u64 best = 0ull;
      for (int i = t; i < M_ / 4; i += 512) {
        const float4 v = sc4[i];
        const float ss[4] = {v.x, v.y, v.z, v.w};
#pragma unroll
        for (int c = 0; c < 4; ++c) {
          if (ss[c] > SCORE_T) {
            const u32 bb = __float_as_uint(ss[c]);
            if (bb < X) {
              const int j = i * 4 + c;
              if (!((bitmap[j >> 6] >> (j & 63)) & 1ull)) {
                const u64 key = ((u64)bb << 16) | (u64)(65535 - j);
                if (key > best) best = key;
              }
            }
          }
        }
      }
      red2[t] = best;
      __syncthreads();
      for (int off = 256; off > 0; off >>= 1) {
        if (t < off && red2[t + off] > red2[t]) red2[t] = red2[t + off];
        __syncthreads();
      }
      const u64 wkey = red2[0];
      if (wkey == 0ull) break;
      if (t == 0) {
        const int j = 65535 - (int)(wkey & 0xFFFFull);
        bitmap[j >> 6] |= 1ull << (j & 63);
        const int cls = (j & 3) + 1;
        const float4 bx = boxes4[(size_t)b * M_ + j];
        const float offv = (float)cls * maxv1;
        const float ox1 = bx.x + offv, oy1 = bx.y + offv;
        const float ox2 = bx.z + offv, oy2 = bx.w + offv;
        const float ar = (ox2 - ox1) * (oy2 - oy1);
        bool sup = false;
        for (int k2 = 0; k2 < kcount_s; ++k2) {
          const int ki = aphys(kidx[k2]);
          const float4 kb = cb4[ki];
          const float ltx = fmaxf(kb.x, ox1);
          const float lty = fmaxf(kb.y, oy1);
          const float rbx = fminf(kb.z, ox2);
          const float rby = fminf(kb.w, oy2);
          const float iw = fmaxf(rbx - ltx, 0.f);
          const float ih = fmaxf(rby - lty, 0.f);
          const float inter = iw * ih;
          const float iou = inter / (carea[ki] + ar - inter);
          if (iou > 0.5f) { sup = true; break; }
        }
        if (!sup) {
          const int slot = CAP + nslow_s;        // aphys(slot) == slot
          cb4[slot] = make_float4(ox1, oy1, ox2, oy2);
          carea[slot] = ar;
          cscf[slot] = __uint_as_float((u32)(wkey >> 16));
          cj[slot] = j;
          kidx[kcount_s] = slot;
          ++nslow_s;
          ++kcount_s;
        }
      }
      __syncthreads();
      if (kcount_s >= K_) break;
    }
    __syncthreads();
  }
  __syncthreads();

  // ---- gather outputs ----
  const int kc = kcount_s;
  if (t < K_) {
    const int r = t;
    float ob0 = 0.f, ob1 = 0.f, ob2 = 0.f, ob3 = 0.f;
    float osc = 0.f, olab = 0.f, oside = 0.f;
    float od0 = 0.f, od1 = 0.f, od2 = 0.f;
    float ocon = 0.f, okeep = 0.f;
    if (r < kc) {
      const int idx = kidx[r];
      const int ph = aphys(idx);
      const int j = cj[ph];
      const int cls = (j & 3) + 1;
      const int n = b * P_ + (j >> 2);
      const float4 bx = boxes4[(size_t)b * M_ + j];   // unshifted output box
      ob0 = bx.x; ob1 = bx.y; ob2 = bx.z; ob3 = bx.w;
      osc = cscf[ph];
      olab = (float)cls;
      oside = (handside[n * 5 + cls] > 0.f) ? 1.f : 0.f;  // sigmoid>0.5 <=> x>0
      od0 = dxdymag[n * 15 + cls * 3 + 0];
      od1 = dxdymag[n * 15 + cls * 3 + 1];
      od2 = dxdymag[n * 15 + cls * 3 + 2];
      float bvv = contact[n * 25 + cls * 5 + 0];
      int best = 0;
#pragma unroll
      for (int i = 1; i < 5; ++i) {
        const float ci = contact[n * 25 + cls * 5 + i];
        if (ci > bvv) { bvv = ci; best = i; }
      }
      ocon = (float)best;
      okeep = 1.f;
    }
    const int gb = b * K_ + r;
    out[gb * 4 + 0] = ob0;
    out[gb * 4 + 1] = ob1;
    out[gb * 4 + 2] = ob2;
    out[gb * 4 + 3] = ob3;
    out[3200 + gb] = osc;
    out[4000 + gb] = olab;
    out[4800 + gb] = oside;
    out[5600 + gb * 3 + 0] = od0;
    out[5600 + gb * 3 + 1] = od1;
    out[5600 + gb * 3 + 2] = od2;
    out[8000 + gb] = ocon;
    out[8800 + gb] = okeep;
  }
}

// ---------------------------------------------------------------------------
extern "C" void kernel_launch(void* const* d_in, const int* in_sizes, int n_in,
                              void* d_out, int out_size, void* d_ws, size_t ws_size,
                              hipStream_t stream) {
  const float* class_logits = (const float*)d_in[0];
  const float* box_reg      = (const float*)d_in[1];
  const float* handside     = (const float*)d_in[2];
  const float* dxdymag      = (const float*)d_in[3];
  const float* contact      = (const float*)d_in[4];
  const float* proposals    = (const float*)d_in[5];
  const int*   image_hw     = (const int*)d_in[6];
  float* out = (float*)d_out;

  char* ws = (char*)d_ws;
  u32*   bhist     = (u32*)  ws;                       // 512*576*4 = 1179648 B
  u32*   Xthr      = (u32*)  (ws + 1179648);           // 32 B
  int*   Carr      = (int*)  (ws + 1179680);           // 32 B
  int*   remv      = (int*)  (ws + 1179712);           // 32 B
  int*   offs      = (int*)  (ws + 1179776);           // 2048 B
  float* wblockmax = (float*)(ws + 1181824);           // 2048 B
  u64*   keybuf    = (u64*)  (ws + 1183872);           // 16384 B
  float* wscores   = (float*)(ws + 2097152);           // 2 MiB
  float* wboxes    = (float*)(ws + 4194304);           // 8 MiB (ends 12 MiB)

  prep_kernel<<<dim3(512), dim3(256), 0, stream>>>(
      class_logits, box_reg, proposals, image_hw, wboxes, wscores, wblockmax, bhist);
  thresh_kernel<<<dim3(B_), dim3(512), 0, stream>>>(bhist, Xthr, Carr, remv, offs);
  compact_kernel<<<dim3(512), dim3(256), 0, stream>>>(wscores, Xthr, offs, keybuf);
  nms_kernel<<<dim3(B_), dim3(512), 0, stream>>>(
      wboxes, wscores, wblockmax, Xthr, remv, Carr, keybuf,
      handside, dxdymag, contact, out);
}